// Round 3
// baseline (531.129 us; speedup 1.0000x reference)
//
#include <hip/hip_runtime.h>
#include <hip/hip_bf16.h>
#include <cstdint>
#include <cstddef>

#define T_TOK 2048
#define DIM   1024
#define FDIM  2048
#define NEXP  8

#define GU_MAX 64   // ceil-sum routed tiles(128) <= 23, + 16 shared
#define DN_MAX 64   // <= 23 * 2 K-splits

typedef short  short8  __attribute__((ext_vector_type(8)));
typedef float  floatx4 __attribute__((ext_vector_type(4)));

__device__ inline unsigned short f2bf(float f) {
    unsigned int u = __builtin_bit_cast(unsigned int, f);
    unsigned int r = (u + 0x7FFFu + ((u >> 16) & 1u)) >> 16;  // RNE
    return (unsigned short)r;
}

// async global->LDS, 16B per lane; LDS side is wave-uniform base + lane*16
__device__ inline void glds16(const void* g, void* l) {
    __builtin_amdgcn_global_load_lds(
        (const __attribute__((address_space(1))) unsigned int*)g,
        (__attribute__((address_space(3))) unsigned int*)l, 16, 0, 0);
}

// ---------------- Kernel: router + bf16 activation prep ----------------
__global__ __launch_bounds__(256) void k_router(
    const float* __restrict__ h, const float* __restrict__ rw,
    int* __restrict__ counts, int* __restrict__ lists,
    unsigned short* __restrict__ hb, unsigned short* __restrict__ xb)
{
    int w = threadIdx.x >> 6, lane = threadIdx.x & 63;
    int t = blockIdx.x * 4 + w;
    const float* hrow = h + (size_t)t * DIM;
    float hv[16];
    #pragma unroll
    for (int i = 0; i < 16; ++i) hv[i] = hrow[lane + 64 * i];
    float acc[NEXP];
    #pragma unroll
    for (int e = 0; e < NEXP; ++e) {
        const float* r = rw + (size_t)e * DIM;
        float s = 0.f;
        #pragma unroll
        for (int i = 0; i < 16; ++i) s += hv[i] * r[lane + 64 * i];
        acc[e] = s;
    }
    #pragma unroll
    for (int e = 0; e < NEXP; ++e) {
        float s = acc[e];
        for (int off = 32; off > 0; off >>= 1) s += __shfl_down(s, off);
        acc[e] = s;
    }
    float score = 0.f;
    if (lane == 0) {
        int be = 0; float bv = acc[0];
        #pragma unroll
        for (int e = 1; e < NEXP; ++e) if (acc[e] > bv) { bv = acc[e]; be = e; }
        score = 1.f / (1.f + __expf(-bv));
        int pos = atomicAdd(&counts[be], 1);
        lists[be * T_TOK + pos] = t;
    }
    score = __shfl(score, 0);
    unsigned short* hbr = hb + (size_t)t * DIM;
    unsigned short* xbr = xb + (size_t)t * DIM;
    #pragma unroll
    for (int i = 0; i < 16; ++i) {
        hbr[lane + 64 * i] = f2bf(hv[i]);
        xbr[lane + 64 * i] = f2bf(score * hv[i]);
    }
}

// ---------------- Kernel: compact tile scheduler (128-row tiles) --------
__global__ void k_schedule(const int* __restrict__ counts,
                           int* __restrict__ gu, int* __restrict__ dn)
{
    if (threadIdx.x != 0 || blockIdx.x != 0) return;
    int n = 0;
    for (int e = 0; e < NEXP; ++e) {
        int c = counts[e];
        for (int r = 0; r < c; r += 128) gu[n++] = (e << 16) | r;
    }
    for (int r = 0; r < T_TOK; r += 128) gu[n++] = (NEXP << 16) | r;
    while (n < GU_MAX) gu[n++] = -1;
    n = 0;
    for (int e = 0; e < NEXP; ++e) {
        int c = counts[e];
        for (int r = 0; r < c; r += 128) {
            dn[n++] = (e << 16) | r;               // ks=0: routed half of Hc
            dn[n++] = (1 << 28) | (e << 16) | r;   // ks=1: shared half
        }
    }
    while (n < DN_MAX) dn[n++] = -1;
}

// ------------- Kernel: weight fp32 -> bf16 transpose (gate/up) ----------
// All 18 matrices are [K=1024][N=2048] fp32 -> [N=2048][K=1024] bf16.
__global__ __launch_bounds__(256) void k_cvt_gu(
    const float* __restrict__ wg, const float* __restrict__ wu,
    const float* __restrict__ wsg, const float* __restrict__ wsu,
    unsigned short* __restrict__ wgT, unsigned short* __restrict__ wuT,
    unsigned short* __restrict__ wsgT, unsigned short* __restrict__ wsuT)
{
    int z = blockIdx.y;
    const float* src; unsigned short* dst;
    if (z < NEXP)        { src = wg + (size_t)z * DIM * FDIM;          dst = wgT + (size_t)z * FDIM * DIM; }
    else if (z < 2*NEXP) { src = wu + (size_t)(z - NEXP) * DIM * FDIM; dst = wuT + (size_t)(z - NEXP) * FDIM * DIM; }
    else if (z == 2*NEXP){ src = wsg; dst = wsgT; }
    else                 { src = wsu; dst = wsuT; }
    int n  = blockIdx.x * 64 + (threadIdx.x >> 2);
    int kg = (threadIdx.x & 3) * 8;
    for (int k0 = 0; k0 < DIM; k0 += 32) {
        int k = k0 + kg;
        float v[8];
        #pragma unroll
        for (int j = 0; j < 8; ++j) v[j] = src[(size_t)(k + j) * FDIM + n];
        unsigned int p[4];
        #pragma unroll
        for (int j = 0; j < 4; ++j)
            p[j] = (unsigned)f2bf(v[2*j]) | ((unsigned)f2bf(v[2*j+1]) << 16);
        *(uint4*)&dst[(size_t)n * DIM + k] = make_uint4(p[0], p[1], p[2], p[3]);
    }
}

// ------------- Kernel: weight fp32 -> bf16 transpose (down) -------------
// 9 matrices [K=2048][N=1024] fp32 -> [N=1024][K=2048] bf16.
__global__ __launch_bounds__(256) void k_cvt_dn(
    const float* __restrict__ wd, const float* __restrict__ wsd,
    unsigned short* __restrict__ wdT, unsigned short* __restrict__ wsdT)
{
    int z = blockIdx.y;
    const float* src = (z < NEXP) ? wd + (size_t)z * FDIM * DIM : wsd;
    unsigned short* dst = (z < NEXP) ? wdT + (size_t)z * DIM * FDIM : wsdT;
    int n  = blockIdx.x * 64 + (threadIdx.x >> 2);
    int kg = (threadIdx.x & 3) * 8;
    for (int k0 = 0; k0 < FDIM; k0 += 32) {
        int k = k0 + kg;
        float v[8];
        #pragma unroll
        for (int j = 0; j < 8; ++j) v[j] = src[(size_t)(k + j) * DIM + n];
        unsigned int p[4];
        #pragma unroll
        for (int j = 0; j < 4; ++j)
            p[j] = (unsigned)f2bf(v[2*j]) | ((unsigned)f2bf(v[2*j+1]) << 16);
        *(uint4*)&dst[(size_t)n * FDIM + k] = make_uint4(p[0], p[1], p[2], p[3]);
    }
}

// ---------------- Kernel: gate/up GEMM + silu*mul -> Hc -----------------
// 128x128 tile, bf16 weights [n][k], global_load_lds staging, XOR-swizzled
// unpadded LDS (2-way bank aliasing = free).
__global__ __launch_bounds__(256) void k_gateup(
    const unsigned short* __restrict__ xb, const unsigned short* __restrict__ hb,
    const unsigned short* __restrict__ wgT, const unsigned short* __restrict__ wuT,
    const unsigned short* __restrict__ wsgT, const unsigned short* __restrict__ wsuT,
    const int* __restrict__ counts, const int* __restrict__ lists,
    const int* __restrict__ gu_tiles, unsigned short* __restrict__ Hc)
{
    int ent = gu_tiles[blockIdx.y];
    if (ent < 0) return;
    int e = ent >> 16, row0 = ent & 0xffff;
    bool sh = (e == NEXP);
    int cnt = sh ? T_TOK : counts[e];
    const unsigned short* Asrc = sh ? hb : xb;
    const unsigned short* Bg = sh ? wsgT : wgT + (size_t)e * FDIM * DIM;
    const unsigned short* Bu = sh ? wsuT : wuT + (size_t)e * FDIM * DIM;
    int outoff = sh ? FDIM : 0;
    int col0 = blockIdx.x * 128;

    __shared__ int toks[128];
    __shared__ __align__(16) unsigned short As [128 * 32];
    __shared__ __align__(16) unsigned short Bgs[128 * 32];
    __shared__ __align__(16) unsigned short Bus[128 * 32];

    int tid = threadIdx.x;
    if (tid < 128) {
        int r = row0 + tid;
        toks[tid] = (r < cnt) ? (sh ? r : lists[e * T_TOK + r]) : -1;
    }
    __syncthreads();

    int lane = tid & 63, w = tid >> 6;
    int wm = w >> 1, wn = w & 1;

    // staging constants: it covers 256 lanes each; (row, swizzled k-group)
    int rw_[2], kg_[2], atk[2];
    #pragma unroll
    for (int it = 0; it < 2; ++it) {
        int tt = tid + it * 256;
        int rr = tt >> 2, sq = tt & 3;
        rw_[it] = rr;
        kg_[it] = (sq ^ ((rr >> 1) & 3)) * 8;
        int tk = toks[rr];
        atk[it] = tk < 0 ? 0 : tk;  // clamp: dead rows load row 0, masked in epilogue
    }

    floatx4 accg[4][4], accu[4][4];
    #pragma unroll
    for (int mi = 0; mi < 4; ++mi)
    #pragma unroll
    for (int ni = 0; ni < 4; ++ni) {
        floatx4 z = {0.f, 0.f, 0.f, 0.f};
        accg[mi][ni] = z; accu[mi][ni] = z;
    }

    for (int k0 = 0; k0 < DIM; k0 += 32) {
        __syncthreads();
        #pragma unroll
        for (int it = 0; it < 2; ++it) {
            int loff = (tid + it * 256) * 8;
            glds16(Asrc + (size_t)atk[it] * DIM + k0 + kg_[it], &As[loff]);
            glds16(Bg + (size_t)(col0 + rw_[it]) * DIM + k0 + kg_[it], &Bgs[loff]);
            glds16(Bu + (size_t)(col0 + rw_[it]) * DIM + k0 + kg_[it], &Bus[loff]);
        }
        __syncthreads();

        int kb = (lane >> 4) * 8;
        short8 af[4], bgf[4], buf_[4];
        #pragma unroll
        for (int mi = 0; mi < 4; ++mi) {
            int r = wm * 64 + mi * 16 + (lane & 15);
            int slot = (((kb >> 3) ^ ((r >> 1) & 3))) * 8;
            af[mi] = *(const short8*)&As[r * 32 + slot];
        }
        #pragma unroll
        for (int ni = 0; ni < 4; ++ni) {
            int n = wn * 64 + ni * 16 + (lane & 15);
            int slot = (((kb >> 3) ^ ((n >> 1) & 3))) * 8;
            bgf[ni]  = *(const short8*)&Bgs[n * 32 + slot];
            buf_[ni] = *(const short8*)&Bus[n * 32 + slot];
        }
        #pragma unroll
        for (int mi = 0; mi < 4; ++mi)
        #pragma unroll
        for (int ni = 0; ni < 4; ++ni) {
            accg[mi][ni] = __builtin_amdgcn_mfma_f32_16x16x32_bf16(af[mi], bgf[ni],  accg[mi][ni], 0, 0, 0);
            accu[mi][ni] = __builtin_amdgcn_mfma_f32_16x16x32_bf16(af[mi], buf_[ni], accu[mi][ni], 0, 0, 0);
        }
    }

    #pragma unroll
    for (int mi = 0; mi < 4; ++mi)
    #pragma unroll
    for (int ni = 0; ni < 4; ++ni)
    #pragma unroll
    for (int r = 0; r < 4; ++r) {
        int row = wm * 64 + mi * 16 + (lane >> 4) * 4 + r;
        int tok = toks[row];
        if (tok < 0) continue;
        int col = col0 + wn * 64 + ni * 16 + (lane & 15);
        float g = accg[mi][ni][r], u = accu[mi][ni][r];
        float hval = (g / (1.f + __expf(-g))) * u;
        Hc[(size_t)tok * (2 * FDIM) + outoff + col] = f2bf(hval);
    }
}

// ---------------- Kernel: down-proj, split-K=2, atomic accumulate -------
__global__ __launch_bounds__(256) void k_down(
    const unsigned short* __restrict__ Hc,
    const unsigned short* __restrict__ wdT, const unsigned short* __restrict__ wsdT,
    const int* __restrict__ counts, const int* __restrict__ lists,
    const int* __restrict__ dn_tiles, float* __restrict__ out)
{
    int ent = dn_tiles[blockIdx.y];
    if (ent < 0) return;
    int ks = (ent >> 28) & 1, e = (ent >> 16) & 0xff, row0 = ent & 0xffff;
    int cnt = counts[e];
    const unsigned short* B = ks ? wsdT : wdT + (size_t)e * DIM * FDIM;
    int col0 = blockIdx.x * 128;
    size_t abase = (size_t)ks * FDIM;

    __shared__ int toks[128];
    __shared__ __align__(16) unsigned short As[128 * 32];
    __shared__ __align__(16) unsigned short Bs[128 * 32];

    int tid = threadIdx.x;
    if (tid < 128) {
        int r = row0 + tid;
        toks[tid] = (r < cnt) ? lists[e * T_TOK + r] : -1;
    }
    __syncthreads();

    int lane = tid & 63, w = tid >> 6;
    int wm = w >> 1, wn = w & 1;

    int rw_[2], kg_[2], atk[2];
    #pragma unroll
    for (int it = 0; it < 2; ++it) {
        int tt = tid + it * 256;
        int rr = tt >> 2, sq = tt & 3;
        rw_[it] = rr;
        kg_[it] = (sq ^ ((rr >> 1) & 3)) * 8;
        int tk = toks[rr];
        atk[it] = tk < 0 ? 0 : tk;
    }

    floatx4 acc[4][4];
    #pragma unroll
    for (int mi = 0; mi < 4; ++mi)
    #pragma unroll
    for (int ni = 0; ni < 4; ++ni) {
        floatx4 z = {0.f, 0.f, 0.f, 0.f};
        acc[mi][ni] = z;
    }

    for (int k0 = 0; k0 < FDIM; k0 += 32) {
        __syncthreads();
        #pragma unroll
        for (int it = 0; it < 2; ++it) {
            int loff = (tid + it * 256) * 8;
            glds16(Hc + (size_t)atk[it] * (2 * FDIM) + abase + k0 + kg_[it], &As[loff]);
            glds16(B + (size_t)(col0 + rw_[it]) * FDIM + k0 + kg_[it], &Bs[loff]);
        }
        __syncthreads();

        int kb = (lane >> 4) * 8;
        short8 af[4], bf[4];
        #pragma unroll
        for (int mi = 0; mi < 4; ++mi) {
            int r = wm * 64 + mi * 16 + (lane & 15);
            int slot = (((kb >> 3) ^ ((r >> 1) & 3))) * 8;
            af[mi] = *(const short8*)&As[r * 32 + slot];
        }
        #pragma unroll
        for (int ni = 0; ni < 4; ++ni) {
            int n = wn * 64 + ni * 16 + (lane & 15);
            int slot = (((kb >> 3) ^ ((n >> 1) & 3))) * 8;
            bf[ni] = *(const short8*)&Bs[n * 32 + slot];
        }
        #pragma unroll
        for (int mi = 0; mi < 4; ++mi)
        #pragma unroll
        for (int ni = 0; ni < 4; ++ni)
            acc[mi][ni] = __builtin_amdgcn_mfma_f32_16x16x32_bf16(af[mi], bf[ni], acc[mi][ni], 0, 0, 0);
    }

    #pragma unroll
    for (int mi = 0; mi < 4; ++mi)
    #pragma unroll
    for (int ni = 0; ni < 4; ++ni)
    #pragma unroll
    for (int r = 0; r < 4; ++r) {
        int row = wm * 64 + mi * 16 + (lane >> 4) * 4 + r;
        int tok = toks[row];
        if (tok < 0) continue;
        int col = col0 + wn * 64 + ni * 16 + (lane & 15);
        atomicAdd(&out[(size_t)tok * DIM + col], acc[mi][ni][r]);
    }
}

extern "C" void kernel_launch(void* const* d_in, const int* in_sizes, int n_in,
                              void* d_out, int out_size, void* d_ws, size_t ws_size,
                              hipStream_t stream)
{
    const float* h   = (const float*)d_in[0];
    const float* rw  = (const float*)d_in[1];
    const float* wg  = (const float*)d_in[2];
    const float* wu  = (const float*)d_in[3];
    const float* wd  = (const float*)d_in[4];
    const float* wsg = (const float*)d_in[5];
    const float* wsu = (const float*)d_in[6];
    const float* wsd = (const float*)d_in[7];
    float* out = (float*)d_out;

    const size_t MB = 1024 * 1024;
    char* ws = (char*)d_ws;
    int* counts   = (int*)ws;
    int* gu_tiles = (int*)(ws + 256);
    int* dn_tiles = (int*)(ws + 1024);
    int* lists    = (int*)(ws + 2048);                       // 64 KB
    unsigned short* hb  = (unsigned short*)(ws + 131072);    // 4 MB  [T][D]
    unsigned short* xb  = (unsigned short*)(ws + 131072 + 4*MB);   // 4 MB
    unsigned short* Hc  = (unsigned short*)(ws + 131072 + 8*MB);   // 16 MB [T][2F]
    char* W = ws + 131072 + 24 * MB;
    unsigned short* wgT  = (unsigned short*)(W);             // 32 MB [E][F][D]
    unsigned short* wuT  = (unsigned short*)(W + 32*MB);     // 32 MB
    unsigned short* wsgT = (unsigned short*)(W + 64*MB);     // 4 MB [FS][D]
    unsigned short* wsuT = (unsigned short*)(W + 68*MB);     // 4 MB
    // down weights alias the gate/up region (converted after k_gateup runs)
    unsigned short* wdT  = (unsigned short*)(W);             // 32 MB [E][D][F]
    unsigned short* wsdT = (unsigned short*)(W + 32*MB);     // 4 MB [D][FS]

    hipMemsetAsync(counts, 0, 64, stream);
    hipMemsetAsync(out, 0, (size_t)T_TOK * DIM * sizeof(float), stream);
    k_cvt_gu<<<dim3(FDIM / 64, 2 * NEXP + 2), 256, 0, stream>>>(
        wg, wu, wsg, wsu, wgT, wuT, wsgT, wsuT);
    k_router<<<dim3(T_TOK / 4), 256, 0, stream>>>(h, rw, counts, lists, hb, xb);
    k_schedule<<<dim3(1), 64, 0, stream>>>(counts, gu_tiles, dn_tiles);
    k_gateup<<<dim3(FDIM / 128, GU_MAX), 256, 0, stream>>>(
        xb, hb, wgT, wuT, wsgT, wsuT, counts, lists, gu_tiles, Hc);
    k_cvt_dn<<<dim3(DIM / 64, NEXP + 1), 256, 0, stream>>>(wd, wsd, wdT, wsdT);
    k_down<<<dim3(DIM / 128, DN_MAX), 256, 0, stream>>>(
        Hc, wdT, wsdT, counts, lists, dn_tiles, out);
}

// Round 5
// 413.976 us; speedup vs baseline: 1.2830x; 1.2830x over previous
//
#include <hip/hip_runtime.h>
#include <hip/hip_bf16.h>
#include <cstdint>
#include <cstddef>

#define T_TOK 2048
#define DIM   1024
#define FDIM  2048
#define NEXP  8

#define GU_MAX 48   // sum ceil(cnt/128) <= 24 routed + 16 shared
#define DN_MAX 64   // <= 24 * 2 K-splits

typedef short  short8  __attribute__((ext_vector_type(8)));
typedef float  floatx4 __attribute__((ext_vector_type(4)));

__device__ inline unsigned short f2bf(float f) {
    unsigned int u = __builtin_bit_cast(unsigned int, f);
    unsigned int r = (u + 0x7FFFu + ((u >> 16) & 1u)) >> 16;  // RNE
    return (unsigned short)r;
}

__device__ inline unsigned int pk2bf(float a, float b) {
    return (unsigned int)f2bf(a) | ((unsigned int)f2bf(b) << 16);
}

// async global->LDS 16B/lane; lds base MUST be wave-uniform (HW: base + lane*16)
__device__ inline void glds16(const void* g, const unsigned short* lds_base, int elem_off) {
    int u = __builtin_amdgcn_readfirstlane(elem_off);  // force SGPR: no waterfall
    __builtin_amdgcn_global_load_lds(
        (const __attribute__((address_space(1))) unsigned int*)g,
        (__attribute__((address_space(3))) unsigned int*)(lds_base + u), 16, 0, 0);
}

// ---------------- Kernel: router + bf16 activation prep ----------------
__global__ __launch_bounds__(256) void k_router(
    const float* __restrict__ h, const float* __restrict__ rw,
    int* __restrict__ counts, int* __restrict__ lists,
    unsigned short* __restrict__ hb, unsigned short* __restrict__ xb)
{
    int w = threadIdx.x >> 6, lane = threadIdx.x & 63;
    int t = blockIdx.x * 4 + w;
    const float* hrow = h + (size_t)t * DIM;
    float hv[16];
    #pragma unroll
    for (int i = 0; i < 16; ++i) hv[i] = hrow[lane + 64 * i];
    float acc[NEXP];
    #pragma unroll
    for (int e = 0; e < NEXP; ++e) {
        const float* r = rw + (size_t)e * DIM;
        float s = 0.f;
        #pragma unroll
        for (int i = 0; i < 16; ++i) s += hv[i] * r[lane + 64 * i];
        acc[e] = s;
    }
    #pragma unroll
    for (int e = 0; e < NEXP; ++e) {
        float s = acc[e];
        for (int off = 32; off > 0; off >>= 1) s += __shfl_down(s, off);
        acc[e] = s;
    }
    float score = 0.f;
    if (lane == 0) {
        int be = 0; float bv = acc[0];
        #pragma unroll
        for (int e = 1; e < NEXP; ++e) if (acc[e] > bv) { bv = acc[e]; be = e; }
        score = 1.f / (1.f + __expf(-bv));
        int pos = atomicAdd(&counts[be], 1);
        lists[be * T_TOK + pos] = t;
    }
    score = __shfl(score, 0);
    unsigned short* hbr = hb + (size_t)t * DIM;
    unsigned short* xbr = xb + (size_t)t * DIM;
    #pragma unroll
    for (int i = 0; i < 16; ++i) {
        hbr[lane + 64 * i] = f2bf(hv[i]);
        xbr[lane + 64 * i] = f2bf(score * hv[i]);
    }
}

// ---------------- Kernel: compact tile scheduler (128-row tiles) --------
__global__ void k_schedule(const int* __restrict__ counts,
                           int* __restrict__ gu, int* __restrict__ dn)
{
    if (threadIdx.x != 0 || blockIdx.x != 0) return;
    int n = 0;
    for (int e = 0; e < NEXP; ++e) {
        int c = counts[e];
        for (int r = 0; r < c; r += 128) gu[n++] = (e << 16) | r;
    }
    for (int r = 0; r < T_TOK; r += 128) gu[n++] = (NEXP << 16) | r;
    while (n < GU_MAX) gu[n++] = -1;
    n = 0;
    for (int e = 0; e < NEXP; ++e) {
        int c = counts[e];
        for (int r = 0; r < c; r += 128) {
            dn[n++] = (e << 16) | r;               // ks=0: routed half of Hc
            dn[n++] = (1 << 28) | (e << 16) | r;   // ks=1: shared half
        }
    }
    while (n < DN_MAX) dn[n++] = -1;
}

// ---------------- Kernel: fused gate/up GEMM + silu*mul -> Hc ----------
// 128x128 tile, K=1024, BK=32. Weights read fp32 (coalesced), converted to
// bf16 in-register, LDS double-buffered, single barrier per K-iter.
__global__ __launch_bounds__(256, 2) void k_gateup(
    const unsigned short* __restrict__ xb, const unsigned short* __restrict__ hb,
    const float* __restrict__ w_gate, const float* __restrict__ w_up,
    const float* __restrict__ ws_gate, const float* __restrict__ ws_up,
    const int* __restrict__ counts, const int* __restrict__ lists,
    const int* __restrict__ gu_tiles, unsigned short* __restrict__ Hc)
{
    int ent = gu_tiles[blockIdx.y];
    if (ent < 0) return;
    int e = ent >> 16, row0 = ent & 0xffff;
    bool sh = (e == NEXP);
    int cnt = sh ? T_TOK : counts[e];
    const unsigned short* Asrc = sh ? hb : xb;
    const float* Bg = sh ? ws_gate : w_gate + (size_t)e * DIM * FDIM;
    const float* Bu = sh ? ws_up   : w_up   + (size_t)e * DIM * FDIM;
    int outoff = sh ? FDIM : 0;
    int col0 = blockIdx.x * 128;

    __shared__ int toks[128];
    __shared__ __align__(16) unsigned short As [2][128 * 32];
    __shared__ __align__(16) unsigned short Bgs[2][128 * 32];
    __shared__ __align__(16) unsigned short Bus[2][128 * 32];

    int tid = threadIdx.x;
    if (tid < 128) {
        int r = row0 + tid;
        toks[tid] = (r < cnt) ? (sh ? r : lists[e * T_TOK + r]) : -1;
    }
    __syncthreads();

    int lane = tid & 63, w = tid >> 6;
    int wm = w >> 1, wn = w & 1;

    // A staging: 2 rounds of glds16; global granule XOR-swizzled per row
    size_t agoff[2]; int albase[2];
    #pragma unroll
    for (int it = 0; it < 2; ++it) {
        int tt = tid + it * 256;
        int rr = tt >> 2, sq = tt & 3;
        int kg = (sq ^ ((rr >> 1) & 3)) * 8;
        int tk = toks[rr]; if (tk < 0) tk = 0;
        agoff[it] = (size_t)tk * DIM + kg;
        albase[it] = (it * 256 + w * 64) * 8;   // wave-uniform short offset
    }

    // B staging: thread owns cols {2c, 2c+1}, k-granule = wave id
    int c = tid & 63;
    int kq = w;
    int slotB = (kq ^ (c & 3)) * 8;
    const float* bgp = Bg + (size_t)(kq * 8) * FDIM + col0 + 2 * c;
    const float* bup = Bu + (size_t)(kq * 8) * FDIM + col0 + 2 * c;

    float2 gx[8], ux[8];
    auto loadB = [&](int k0) {
        const float* pg = bgp + (size_t)k0 * FDIM;
        const float* pu = bup + (size_t)k0 * FDIM;
        #pragma unroll
        for (int j = 0; j < 8; ++j) {
            gx[j] = *(const float2*)(pg + (size_t)j * FDIM);
            ux[j] = *(const float2*)(pu + (size_t)j * FDIM);
        }
    };
    auto commitB = [&](int p) {
        unsigned int ge[4], go[4], ue[4], uo[4];
        #pragma unroll
        for (int j = 0; j < 4; ++j) {
            ge[j] = pk2bf(gx[2*j].x, gx[2*j+1].x);
            go[j] = pk2bf(gx[2*j].y, gx[2*j+1].y);
            ue[j] = pk2bf(ux[2*j].x, ux[2*j+1].x);
            uo[j] = pk2bf(ux[2*j].y, ux[2*j+1].y);
        }
        *(uint4*)&Bgs[p][(2*c)   * 32 + slotB] = make_uint4(ge[0], ge[1], ge[2], ge[3]);
        *(uint4*)&Bgs[p][(2*c+1) * 32 + slotB] = make_uint4(go[0], go[1], go[2], go[3]);
        *(uint4*)&Bus[p][(2*c)   * 32 + slotB] = make_uint4(ue[0], ue[1], ue[2], ue[3]);
        *(uint4*)&Bus[p][(2*c+1) * 32 + slotB] = make_uint4(uo[0], uo[1], uo[2], uo[3]);
    };
    auto loadA = [&](int k0, int p) {
        #pragma unroll
        for (int it = 0; it < 2; ++it)
            glds16(Asrc + agoff[it] + k0, &As[p][0], albase[it]);
    };

    floatx4 accg[4][4], accu[4][4];
    #pragma unroll
    for (int mi = 0; mi < 4; ++mi)
    #pragma unroll
    for (int ni = 0; ni < 4; ++ni) {
        floatx4 z = {0.f, 0.f, 0.f, 0.f};
        accg[mi][ni] = z; accu[mi][ni] = z;
    }

    // prologue: buf0 <- tile 0; regs <- tile 1
    loadA(0, 0);
    loadB(0);
    commitB(0);
    loadB(32);

    int p = 0;
    for (int k0 = 0; k0 < DIM; k0 += 32) {
        __syncthreads();   // tile(k0) staged in buf p
        int nk = k0 + 32;
        if (nk < DIM) {
            loadA(nk, p ^ 1);
            commitB(p ^ 1);          // uses regs prefetched last iter
            if (nk + 32 < DIM) loadB(nk + 32);
        }
        int kb = (lane >> 4) * 8;
        short8 af[4], bgf[4], buf_[4];
        #pragma unroll
        for (int mi = 0; mi < 4; ++mi) {
            int r = wm * 64 + mi * 16 + (lane & 15);
            int slot = ((kb >> 3) ^ ((r >> 1) & 3)) * 8;
            af[mi] = *(const short8*)&As[p][r * 32 + slot];
        }
        #pragma unroll
        for (int ni = 0; ni < 4; ++ni) {
            int n = wn * 64 + ni * 16 + (lane & 15);
            int slot = ((kb >> 3) ^ ((n >> 1) & 3)) * 8;
            bgf[ni]  = *(const short8*)&Bgs[p][n * 32 + slot];
            buf_[ni] = *(const short8*)&Bus[p][n * 32 + slot];
        }
        #pragma unroll
        for (int mi = 0; mi < 4; ++mi)
        #pragma unroll
        for (int ni = 0; ni < 4; ++ni) {
            accg[mi][ni] = __builtin_amdgcn_mfma_f32_16x16x32_bf16(af[mi], bgf[ni],  accg[mi][ni], 0, 0, 0);
            accu[mi][ni] = __builtin_amdgcn_mfma_f32_16x16x32_bf16(af[mi], buf_[ni], accu[mi][ni], 0, 0, 0);
        }
        p ^= 1;
    }

    #pragma unroll
    for (int mi = 0; mi < 4; ++mi)
    #pragma unroll
    for (int ni = 0; ni < 4; ++ni)
    #pragma unroll
    for (int r = 0; r < 4; ++r) {
        int row = wm * 64 + mi * 16 + (lane >> 4) * 4 + r;
        int tok = toks[row];
        if (tok < 0) continue;
        int col = col0 + wn * 64 + ni * 16 + (lane & 15);
        float g = accg[mi][ni][r], u = accu[mi][ni][r];
        float hval = (g / (1.f + __expf(-g))) * u;
        Hc[(size_t)tok * (2 * FDIM) + outoff + col] = f2bf(hval);
    }
}

// ---------------- Kernel: fused down-proj, split-K=2, atomic -----------
// 128x64 tile, K=2048, BK=32; same pipeline as k_gateup.
__global__ __launch_bounds__(256) void k_down(
    const unsigned short* __restrict__ Hc,
    const float* __restrict__ w_down, const float* __restrict__ ws_down,
    const int* __restrict__ counts, const int* __restrict__ lists,
    const int* __restrict__ dn_tiles, float* __restrict__ out)
{
    int ent = dn_tiles[blockIdx.y];
    if (ent < 0) return;
    int ks = (ent >> 28) & 1, e = (ent >> 16) & 0xff, row0 = ent & 0xffff;
    int cnt = counts[e];
    const float* B = ks ? ws_down : w_down + (size_t)e * FDIM * DIM;
    int col0 = blockIdx.x * 64;
    size_t abase = (size_t)ks * FDIM;

    __shared__ int toks[128];
    __shared__ __align__(16) unsigned short As[2][128 * 32];
    __shared__ __align__(16) unsigned short Bs[2][64 * 32];

    int tid = threadIdx.x;
    if (tid < 128) {
        int r = row0 + tid;
        toks[tid] = (r < cnt) ? lists[e * T_TOK + r] : -1;
    }
    __syncthreads();

    int lane = tid & 63, w = tid >> 6;
    int wm = w >> 1, wn = w & 1;

    size_t agoff[2]; int albase[2];
    #pragma unroll
    for (int it = 0; it < 2; ++it) {
        int tt = tid + it * 256;
        int rr = tt >> 2, sq = tt & 3;
        int kg = (sq ^ ((rr >> 1) & 3)) * 8;
        int tk = toks[rr]; if (tk < 0) tk = 0;
        agoff[it] = (size_t)tk * (2 * FDIM) + abase + kg;
        albase[it] = (it * 256 + w * 64) * 8;
    }

    int c = tid & 63;          // single col c
    int kq = w;
    int slotB = (kq ^ ((c >> 1) & 3)) * 8;
    const float* bp = B + (size_t)(kq * 8) * DIM + col0 + c;

    float bx[8];
    auto loadB = [&](int k0) {
        const float* pb = bp + (size_t)k0 * DIM;
        #pragma unroll
        for (int j = 0; j < 8; ++j) bx[j] = pb[(size_t)j * DIM];
    };
    auto commitB = [&](int p) {
        unsigned int bw[4];
        #pragma unroll
        for (int j = 0; j < 4; ++j) bw[j] = pk2bf(bx[2*j], bx[2*j+1]);
        *(uint4*)&Bs[p][c * 32 + slotB] = make_uint4(bw[0], bw[1], bw[2], bw[3]);
    };
    auto loadA = [&](int k0, int p) {
        #pragma unroll
        for (int it = 0; it < 2; ++it)
            glds16(Hc + agoff[it] + k0, &As[p][0], albase[it]);
    };

    floatx4 acc[4][2];
    #pragma unroll
    for (int mi = 0; mi < 4; ++mi)
    #pragma unroll
    for (int ni = 0; ni < 2; ++ni) {
        floatx4 z = {0.f, 0.f, 0.f, 0.f};
        acc[mi][ni] = z;
    }

    loadA(0, 0);
    loadB(0);
    commitB(0);
    loadB(32);

    int p = 0;
    for (int k0 = 0; k0 < FDIM; k0 += 32) {
        __syncthreads();
        int nk = k0 + 32;
        if (nk < FDIM) {
            loadA(nk, p ^ 1);
            commitB(p ^ 1);
            if (nk + 32 < FDIM) loadB(nk + 32);
        }
        int kb = (lane >> 4) * 8;
        short8 af[4], bf[2];
        #pragma unroll
        for (int mi = 0; mi < 4; ++mi) {
            int r = wm * 64 + mi * 16 + (lane & 15);
            int slot = ((kb >> 3) ^ ((r >> 1) & 3)) * 8;
            af[mi] = *(const short8*)&As[p][r * 32 + slot];
        }
        #pragma unroll
        for (int ni = 0; ni < 2; ++ni) {
            int n = wn * 32 + ni * 16 + (lane & 15);
            int slot = ((kb >> 3) ^ ((n >> 1) & 3)) * 8;
            bf[ni] = *(const short8*)&Bs[p][n * 32 + slot];
        }
        #pragma unroll
        for (int mi = 0; mi < 4; ++mi)
        #pragma unroll
        for (int ni = 0; ni < 2; ++ni)
            acc[mi][ni] = __builtin_amdgcn_mfma_f32_16x16x32_bf16(af[mi], bf[ni], acc[mi][ni], 0, 0, 0);
        p ^= 1;
    }

    #pragma unroll
    for (int mi = 0; mi < 4; ++mi)
    #pragma unroll
    for (int ni = 0; ni < 2; ++ni)
    #pragma unroll
    for (int r = 0; r < 4; ++r) {
        int row = wm * 64 + mi * 16 + (lane >> 4) * 4 + r;
        int tok = toks[row];
        if (tok < 0) continue;
        int col = col0 + wn * 32 + ni * 16 + (lane & 15);
        atomicAdd(&out[(size_t)tok * DIM + col], acc[mi][ni][r]);
    }
}

extern "C" void kernel_launch(void* const* d_in, const int* in_sizes, int n_in,
                              void* d_out, int out_size, void* d_ws, size_t ws_size,
                              hipStream_t stream)
{
    const float* h   = (const float*)d_in[0];
    const float* rw  = (const float*)d_in[1];
    const float* wg  = (const float*)d_in[2];
    const float* wu  = (const float*)d_in[3];
    const float* wd  = (const float*)d_in[4];
    const float* wsg = (const float*)d_in[5];
    const float* wsu = (const float*)d_in[6];
    const float* wsd = (const float*)d_in[7];
    float* out = (float*)d_out;

    char* ws = (char*)d_ws;
    int* counts   = (int*)ws;
    int* gu_tiles = (int*)(ws + 256);
    int* dn_tiles = (int*)(ws + 1024);
    int* lists    = (int*)(ws + 2048);                        // 64 KB
    unsigned short* hb = (unsigned short*)(ws + 131072);      // [T][D] bf16, 4 MB
    unsigned short* xb = hb + (size_t)T_TOK * DIM;            // 4 MB
    unsigned short* Hc = xb + (size_t)T_TOK * DIM;            // [T][2F] bf16, 16 MB

    (void)hipMemsetAsync(counts, 0, 64, stream);
    (void)hipMemsetAsync(out, 0, (size_t)T_TOK * DIM * sizeof(float), stream);
    k_router<<<dim3(T_TOK / 4), 256, 0, stream>>>(h, rw, counts, lists, hb, xb);
    k_schedule<<<dim3(1), 64, 0, stream>>>(counts, gu_tiles, dn_tiles);
    k_gateup<<<dim3(FDIM / 128, GU_MAX), 256, 0, stream>>>(
        xb, hb, wg, wu, wsg, wsu, counts, lists, gu_tiles, Hc);
    k_down<<<dim3(DIM / 64, DN_MAX), 256, 0, stream>>>(
        Hc, wd, wsd, counts, lists, dn_tiles, out);
}